// Round 1
// baseline (12973.068 us; speedup 1.0000x reference)
//
#include <hip/hip_runtime.h>

// Dims: B=128, T=512, I=256, H=512, O=256, 3H=1536
// GRU (PyTorch gate order r,z,n), 2 layers sharing one hidden state (quirk),
// y_t = h @ W_out^T + b_out.
//
// Strategy (round 1): per-step kernels, bf16 MFMA (16x16x32) with f32 accum,
// f32 hidden state. Weights pre-converted/packed to bf16 once per call:
//   WL0cat [1536][768]  = [W_ih0 | W_hh0]  (K = 256+512 combined)
//   WL1cat [2048][512]  = [W_ih1_r+W_hh1_r ; W_ih1_z+W_hh1_z ; W_ih1_n ; W_hh1_n]
//   WOutB  [256][512]   = bf16(W_out)
// Per step: L0 kernel (gates+GRU for layer 0, plus fused y(t-1) blocks),
//           L1 kernel (gates+GRU for layer 1). 2 launches/step + prep + tail.

typedef short s16x8 __attribute__((ext_vector_type(8)));  // 8 bf16 (4 VGPRs)
typedef float f32x4 __attribute__((ext_vector_type(4)));  // MFMA C/D frag
typedef unsigned short u16;

#define MFMA(a, b, c) __builtin_amdgcn_mfma_f32_16x16x32_bf16((a), (b), (c), 0, 0, 0)

__device__ __forceinline__ u16 f2bf(float f) {  // f32 -> bf16 RNE
  unsigned u = __builtin_bit_cast(unsigned, f);
  u = u + 0x7fffu + ((u >> 16) & 1u);
  return (u16)(u >> 16);
}
__device__ __forceinline__ float sigm(float x) { return 1.f / (1.f + __expf(-x)); }
__device__ __forceinline__ float tanh_f(float x) { return 1.f - 2.f / (1.f + __expf(2.f * x)); }

// ---------------- weight prep (once per call) ----------------
__global__ void prep_kernel(const float* __restrict__ W_ih0, const float* __restrict__ W_hh0,
                            const float* __restrict__ W_ih1, const float* __restrict__ W_hh1,
                            const float* __restrict__ W_out, const float* __restrict__ h0,
                            u16* __restrict__ WL0, u16* __restrict__ WL1,
                            u16* __restrict__ WOB, u16* __restrict__ HbB,
                            float* __restrict__ HbF) {
  const int n0 = 1536 * 768, n1 = 2048 * 512, n2 = 256 * 512, n3 = 128 * 512;
  const int total = n0 + n1 + n2 + n3;
  for (int i = blockIdx.x * blockDim.x + threadIdx.x; i < total; i += gridDim.x * blockDim.x) {
    if (i < n0) {
      int row = i / 768, c = i % 768;
      float v = (c < 256) ? W_ih0[row * 256 + c] : W_hh0[row * 512 + (c - 256)];
      WL0[i] = f2bf(v);
    } else if (i < n0 + n1) {
      int k2 = i - n0;
      int row = k2 / 512, k = k2 % 512;
      int strip = row >> 9, j = row & 511;
      float v;
      if (strip == 0)      v = W_ih1[j * 512 + k] + W_hh1[j * 512 + k];
      else if (strip == 1) v = W_ih1[(512 + j) * 512 + k] + W_hh1[(512 + j) * 512 + k];
      else if (strip == 2) v = W_ih1[(1024 + j) * 512 + k];
      else                 v = W_hh1[(1024 + j) * 512 + k];
      WL1[k2] = f2bf(v);
    } else if (i < n0 + n1 + n2) {
      int k2 = i - n0 - n1;
      WOB[k2] = f2bf(W_out[k2]);
    } else {
      int k2 = i - n0 - n1 - n2;
      float v = h0[k2];
      HbF[k2] = v;
      HbB[k2] = f2bf(v);
    }
  }
}

// ---------------- layer 0 (+ fused y(t-1)) ----------------
// grid (32, 3) x 256 thr. blockIdx.y<2: L0 gates for 16 h-cols (blockIdx.x) and
// 64 batch rows (blockIdx.y). blockIdx.y==2: y projection for step t-1.
__global__ __launch_bounds__(256) void l0_kernel(
    const float* __restrict__ x, const float* __restrict__ b_ih0,
    const float* __restrict__ b_hh0, const float* __restrict__ b_out,
    const u16* __restrict__ WL0, const u16* __restrict__ WOB,
    const float* __restrict__ HbF, const u16* __restrict__ HbB,
    float* __restrict__ hLF, u16* __restrict__ hLB, float* __restrict__ Y, int t) {
  const int w = threadIdx.x >> 6, l = threadIdx.x & 63;
  const int l15 = l & 15, l4 = l >> 4;

  if (blockIdx.y == 2) {  // y for t-1 (reads Hbuf written by L1(t-1))
    if (t == 0) return;
    int id = blockIdx.x * 4 + w;  // 0..127 tiles, 8 m x 16 n
    int mt = id & 7, nt = id >> 3;
    f32x4 acc = {0.f, 0.f, 0.f, 0.f};
    const u16* arow = HbB + (mt * 16 + l15) * 512 + l4 * 8;
    const u16* brow = WOB + (nt * 16 + l15) * 512 + l4 * 8;
    for (int kt = 0; kt < 16; ++kt)
      acc = MFMA(*(const s16x8*)(arow + kt * 32), *(const s16x8*)(brow + kt * 32), acc);
    int o = nt * 16 + l15;
    float bo = b_out[o];
    int b0 = mt * 16 + l4 * 4;
    for (int j = 0; j < 4; ++j)
      Y[((b0 + j) * 512 + (t - 1)) * 256 + o] = acc[j] + bo;
    return;
  }

  const int cg = blockIdx.x;                 // col group: 16 h-cols
  const int mt = blockIdx.y * 4 + w;         // m-tile 0..7 (16 batch rows)
  f32x4 accR = {0.f, 0.f, 0.f, 0.f}, accZ = {0.f, 0.f, 0.f, 0.f};
  f32x4 accNI = {0.f, 0.f, 0.f, 0.f}, accNH = {0.f, 0.f, 0.f, 0.f};

  const u16* wr = WL0 + (0 * 512 + cg * 16 + l15) * 768 + l4 * 8;
  const u16* wz = WL0 + (1 * 512 + cg * 16 + l15) * 768 + l4 * 8;
  const u16* wn = WL0 + (2 * 512 + cg * 16 + l15) * 768 + l4 * 8;
  const int brow = mt * 16 + l15;
  const float* xrow = x + ((size_t)brow * 512 + t) * 256 + l4 * 8;
  const u16* hrow = HbB + brow * 512 + l4 * 8;

  // x-phase: k = 0..255 (8 k-tiles), convert f32->bf16 on the fly
  for (int kt = 0; kt < 8; ++kt) {
    float4 u = *(const float4*)(xrow + kt * 32);
    float4 v = *(const float4*)(xrow + kt * 32 + 4);
    s16x8 a;
    a[0] = f2bf(u.x); a[1] = f2bf(u.y); a[2] = f2bf(u.z); a[3] = f2bf(u.w);
    a[4] = f2bf(v.x); a[5] = f2bf(v.y); a[6] = f2bf(v.z); a[7] = f2bf(v.w);
    accR  = MFMA(a, *(const s16x8*)(wr + kt * 32), accR);
    accZ  = MFMA(a, *(const s16x8*)(wz + kt * 32), accZ);
    accNI = MFMA(a, *(const s16x8*)(wn + kt * 32), accNI);
  }
  // h-phase: k = 256..767 (16 k-tiles), bf16 hidden state
  for (int kt = 8; kt < 24; ++kt) {
    s16x8 a = *(const s16x8*)(hrow + (kt - 8) * 32);
    accR  = MFMA(a, *(const s16x8*)(wr + kt * 32), accR);
    accZ  = MFMA(a, *(const s16x8*)(wz + kt * 32), accZ);
    accNH = MFMA(a, *(const s16x8*)(wn + kt * 32), accNH);
  }

  const int jg = cg * 16 + l15;
  const float br2 = b_ih0[jg] + b_hh0[jg];
  const float bz2 = b_ih0[512 + jg] + b_hh0[512 + jg];
  const float bni = b_ih0[1024 + jg];
  const float bnh = b_hh0[1024 + jg];
  const int b0 = mt * 16 + l4 * 4;
  for (int j = 0; j < 4; ++j) {
    int bb = b0 + j;
    float r = sigm(accR[j] + br2);
    float z = sigm(accZ[j] + bz2);
    float n = tanh_f(accNI[j] + bni + r * (accNH[j] + bnh));
    float hp = HbF[bb * 512 + jg];
    float h = (1.f - z) * n + z * hp;
    hLF[bb * 512 + jg] = h;
    hLB[bb * 512 + jg] = f2bf(h);
  }
}

// ---------------- layer 1 ----------------
// grid (32, 2) x 256 thr. Input/hidden both = h_l0 (the quirk).
__global__ __launch_bounds__(256) void l1_kernel(
    const float* __restrict__ b_ih1, const float* __restrict__ b_hh1,
    const u16* __restrict__ WL1, const float* __restrict__ hLF,
    const u16* __restrict__ hLB, float* __restrict__ HbF, u16* __restrict__ HbB) {
  const int w = threadIdx.x >> 6, l = threadIdx.x & 63;
  const int l15 = l & 15, l4 = l >> 4;
  const int cg = blockIdx.x;
  const int mt = blockIdx.y * 4 + w;
  f32x4 accR = {0.f, 0.f, 0.f, 0.f}, accZ = {0.f, 0.f, 0.f, 0.f};
  f32x4 accNI = {0.f, 0.f, 0.f, 0.f}, accNH = {0.f, 0.f, 0.f, 0.f};

  const int brow = mt * 16 + l15;
  const u16* arow = hLB + brow * 512 + l4 * 8;
  const u16* w0 = WL1 + (cg * 16 + l15) * 512 + l4 * 8;  // r (pre-summed)
  const u16* w1 = w0 + 512 * 512;                        // z (pre-summed)
  const u16* w2 = w0 + 1024 * 512;                       // i_n
  const u16* w3 = w0 + 1536 * 512;                       // h_n
  for (int kt = 0; kt < 16; ++kt) {
    s16x8 a = *(const s16x8*)(arow + kt * 32);
    accR  = MFMA(a, *(const s16x8*)(w0 + kt * 32), accR);
    accZ  = MFMA(a, *(const s16x8*)(w1 + kt * 32), accZ);
    accNI = MFMA(a, *(const s16x8*)(w2 + kt * 32), accNI);
    accNH = MFMA(a, *(const s16x8*)(w3 + kt * 32), accNH);
  }

  const int jg = cg * 16 + l15;
  const float br2 = b_ih1[jg] + b_hh1[jg];
  const float bz2 = b_ih1[512 + jg] + b_hh1[512 + jg];
  const float bni = b_ih1[1024 + jg];
  const float bnh = b_hh1[1024 + jg];
  const int b0 = mt * 16 + l4 * 4;
  for (int j = 0; j < 4; ++j) {
    int bb = b0 + j;
    float r = sigm(accR[j] + br2);
    float z = sigm(accZ[j] + bz2);
    float n = tanh_f(accNI[j] + bni + r * (accNH[j] + bnh));
    float hp = hLF[bb * 512 + jg];  // "h_prev" for layer 1 is h_l0 (quirk)
    float h = (1.f - z) * n + z * hp;
    HbF[bb * 512 + jg] = h;
    HbB[bb * 512 + jg] = f2bf(h);
  }
}

// ---------------- final y (t = 511) ----------------
__global__ __launch_bounds__(256) void ytail_kernel(const float* __restrict__ b_out,
                                                    const u16* __restrict__ WOB,
                                                    const u16* __restrict__ HbB,
                                                    float* __restrict__ Y) {
  const int w = threadIdx.x >> 6, l = threadIdx.x & 63;
  const int l15 = l & 15, l4 = l >> 4;
  int id = blockIdx.x * 4 + w;
  int mt = id & 7, nt = id >> 3;
  f32x4 acc = {0.f, 0.f, 0.f, 0.f};
  const u16* arow = HbB + (mt * 16 + l15) * 512 + l4 * 8;
  const u16* brow = WOB + (nt * 16 + l15) * 512 + l4 * 8;
  for (int kt = 0; kt < 16; ++kt)
    acc = MFMA(*(const s16x8*)(arow + kt * 32), *(const s16x8*)(brow + kt * 32), acc);
  int o = nt * 16 + l15;
  float bo = b_out[o];
  int b0 = mt * 16 + l4 * 4;
  for (int j = 0; j < 4; ++j)
    Y[((b0 + j) * 512 + 511) * 256 + o] = acc[j] + bo;
}

extern "C" void kernel_launch(void* const* d_in, const int* in_sizes, int n_in,
                              void* d_out, int out_size, void* d_ws, size_t ws_size,
                              hipStream_t stream) {
  const float* x     = (const float*)d_in[0];
  const float* h0    = (const float*)d_in[1];
  const float* W_ih0 = (const float*)d_in[2];
  const float* W_hh0 = (const float*)d_in[3];
  const float* b_ih0 = (const float*)d_in[4];
  const float* b_hh0 = (const float*)d_in[5];
  const float* W_ih1 = (const float*)d_in[6];
  const float* W_hh1 = (const float*)d_in[7];
  const float* b_ih1 = (const float*)d_in[8];
  const float* b_hh1 = (const float*)d_in[9];
  const float* W_out = (const float*)d_in[10];
  const float* b_out = (const float*)d_in[11];
  float* Y = (float*)d_out;

  // ws carve (~5.25 MiB total)
  u16* WL0 = (u16*)d_ws;            // 1536*768
  u16* WL1 = WL0 + 1536 * 768;      // 2048*512
  u16* WOB = WL1 + 2048 * 512;      // 256*512
  u16* HbB = WOB + 256 * 512;       // 128*512
  u16* hLB = HbB + 128 * 512;       // 128*512
  float* HbF = (float*)(hLB + 128 * 512);  // 128*512 f32
  float* hLF = HbF + 128 * 512;            // 128*512 f32

  prep_kernel<<<dim3(1024), dim3(256), 0, stream>>>(W_ih0, W_hh0, W_ih1, W_hh1,
                                                    W_out, h0, WL0, WL1, WOB, HbB, HbF);
  for (int t = 0; t < 512; ++t) {
    l0_kernel<<<dim3(32, 3), dim3(256), 0, stream>>>(x, b_ih0, b_hh0, b_out, WL0,
                                                     WOB, HbF, HbB, hLF, hLB, Y, t);
    l1_kernel<<<dim3(32, 2), dim3(256), 0, stream>>>(b_ih1, b_hh1, WL1, hLF, hLB,
                                                     HbF, HbB);
  }
  ytail_kernel<<<dim3(32), dim3(256), 0, stream>>>(b_out, WOB, HbB, Y);
}